// Round 2
// baseline (604.471 us; speedup 1.0000x reference)
//
#include <hip/hip_runtime.h>
#include <stdint.h>
#include <stddef.h>

#define M_DIM 8192
#define N_DIM 4096
#define K_DIM 4096

#define BM 128
#define BN 128
#define BK 64

typedef __bf16 bf16x8 __attribute__((ext_vector_type(8)));
typedef float f32x4 __attribute__((ext_vector_type(4)));

__device__ __forceinline__ void async_load16(void* lds, const void* g) {
  __builtin_amdgcn_global_load_lds(
      (const __attribute__((address_space(1))) void*)g,
      (__attribute__((address_space(3))) void*)lds,
      16, 0, 0);
}

__device__ __forceinline__ uint16_t f32_to_bf16(float f) {
  union { float f; uint32_t u; } c; c.f = f;
  uint32_t u = c.u;
  u += 0x7FFFu + ((u >> 16) & 1u);   // round-to-nearest-even
  return (uint16_t)(u >> 16);
}

// Detect weight storage: harness contract says integer inputs arrive as int32,
// but sample to be safe. If any of the first 4096 words is outside [-127,127],
// the buffer is int8-packed (flag=1); true int32 weights always fit (flag=0).
__global__ void detect_kernel(const int* __restrict__ w, int* __restrict__ flag) {
  __shared__ int bad;
  if (threadIdx.x == 0) bad = 0;
  __syncthreads();
  int local = 0;
  for (int i = threadIdx.x; i < 4096; i += 256) {
    int v = w[i];
    if (v < -127 || v > 127) local = 1;
  }
  if (local) atomicOr(&bad, 1);
  __syncthreads();
  if (threadIdx.x == 0) *flag = bad;
}

// x: fp32 -> bf16, 8 elems/thread
__global__ void cvt_x_kernel(const float* __restrict__ x, uint16_t* __restrict__ y) {
  size_t i = ((size_t)blockIdx.x * blockDim.x + threadIdx.x) * 8;
  float4 a = *(const float4*)(x + i);
  float4 b = *(const float4*)(x + i + 4);
  union { uint16_t h[8]; uint4 v; } o;
  o.h[0] = f32_to_bf16(a.x); o.h[1] = f32_to_bf16(a.y);
  o.h[2] = f32_to_bf16(a.z); o.h[3] = f32_to_bf16(a.w);
  o.h[4] = f32_to_bf16(b.x); o.h[5] = f32_to_bf16(b.y);
  o.h[6] = f32_to_bf16(b.z); o.h[7] = f32_to_bf16(b.w);
  *(uint4*)(y + i) = o.v;
}

// w -> bf16 (exact: |q|<=127 fits bf16's 8-bit mantissa), 8 elems/thread.
// flag=0: int32 storage (expected). flag=1: int8-packed storage.
__global__ void cvt_w_kernel(const void* __restrict__ w, uint16_t* __restrict__ y,
                             const int* __restrict__ flag) {
  const bool packed8 = (*flag != 0);
  size_t i = ((size_t)blockIdx.x * blockDim.x + threadIdx.x) * 8;
  union { uint16_t h[8]; uint4 v; } o;
  if (!packed8) {
    const int4* p = (const int4*)((const int*)w + i);
    int4 a = p[0], b = p[1];
    o.h[0] = f32_to_bf16((float)a.x); o.h[1] = f32_to_bf16((float)a.y);
    o.h[2] = f32_to_bf16((float)a.z); o.h[3] = f32_to_bf16((float)a.w);
    o.h[4] = f32_to_bf16((float)b.x); o.h[5] = f32_to_bf16((float)b.y);
    o.h[6] = f32_to_bf16((float)b.z); o.h[7] = f32_to_bf16((float)b.w);
  } else {
    union { int2 v; signed char c[8]; } in;
    in.v = *(const int2*)((const signed char*)w + i);
#pragma unroll
    for (int j = 0; j < 8; ++j) o.h[j] = f32_to_bf16((float)in.c[j]);
  }
  *(uint4*)(y + i) = o.v;
}

// C[M,N] = A[M,K] * B[N,K]^T, then scale column n by scaler[n].
// A,B bf16 K-contiguous; 128x128 tile, BK=64, 4 waves (2x2 of 64x64),
// global_load_lds width-16 staging with XOR chunk swizzle.
__global__ __launch_bounds__(256, 2) void gemm_bf16_bt(
    const uint16_t* __restrict__ A, const uint16_t* __restrict__ B,
    const float* __restrict__ scaler, float* __restrict__ C) {
  __shared__ __align__(16) uint8_t sA[BM * BK * 2];  // 16 KiB
  __shared__ __align__(16) uint8_t sB[BN * BK * 2];  // 16 KiB

  const int tile_n = blockIdx.x * BN;
  const int tile_m = blockIdx.y * BM;
  const int w    = threadIdx.x >> 6;
  const int lane = threadIdx.x & 63;
  const int q    = lane >> 4;      // quad 0..3
  const int m16  = lane & 15;
  const int wrow = (w >> 1) * 64;  // wave's 64x64 patch
  const int wcol = (w & 1) * 64;

  f32x4 acc[4][4];
#pragma unroll
  for (int i = 0; i < 4; ++i)
#pragma unroll
    for (int j = 0; j < 4; ++j)
      acc[i][j] = (f32x4){0.f, 0.f, 0.f, 0.f};

  for (int kt = 0; kt < K_DIM; kt += BK) {
    // Stage A then B: 1024 16B-chunks each, 4 rounds x 4 waves x 64 lanes.
    // LDS slot g holds logical chunk (r = g>>3, c = (g&7) ^ (r&7)).
    // lds addr is wave-uniform base + lane*16 (global_load_lds constraint).
#pragma unroll
    for (int p = 0; p < 4; ++p) {
      int g = ((p * 4 + w) << 6) + lane;
      int r = g >> 3;
      int c = (g & 7) ^ (r & 7);
      async_load16(sA + (size_t)g * 16,
                   A + (size_t)(tile_m + r) * K_DIM + kt + c * 8);
    }
#pragma unroll
    for (int p = 0; p < 4; ++p) {
      int g = ((p * 4 + w) << 6) + lane;
      int r = g >> 3;
      int c = (g & 7) ^ (r & 7);
      async_load16(sB + (size_t)g * 16,
                   B + (size_t)(tile_n + r) * K_DIM + kt + c * 8);
    }
    __syncthreads();

#pragma unroll
    for (int ks = 0; ks < 2; ++ks) {
      bf16x8 af[4], bfr[4];
#pragma unroll
      for (int t = 0; t < 4; ++t) {
        int ca = (ks << 2) + q;
        int ra = wrow + t * 16 + m16;
        af[t] = *(const bf16x8*)(sA + (((ra << 3) + (ca ^ (ra & 7))) << 4));
        int rb = wcol + t * 16 + m16;
        bfr[t] = *(const bf16x8*)(sB + (((rb << 3) + (ca ^ (rb & 7))) << 4));
      }
#pragma unroll
      for (int i = 0; i < 4; ++i)
#pragma unroll
        for (int j = 0; j < 4; ++j)
          acc[i][j] = __builtin_amdgcn_mfma_f32_16x16x32_bf16(
              af[i], bfr[j], acc[i][j], 0, 0, 0);
    }
    __syncthreads();
  }

  // Epilogue: C/D layout col=lane&15, row=(lane>>4)*4+reg. Scale by scaler[col].
#pragma unroll
  for (int j = 0; j < 4; ++j) {
    int col = tile_n + wcol + j * 16 + m16;
    float s = scaler[col];
#pragma unroll
    for (int i = 0; i < 4; ++i) {
      int row0 = tile_m + wrow + i * 16 + q * 4;
#pragma unroll
      for (int r = 0; r < 4; ++r)
        C[(size_t)(row0 + r) * N_DIM + col] = acc[i][j][r] * s;
    }
  }
}

// Correct-but-slow insurance if ws_size is too small for bf16 copies.
__global__ void fallback_kernel(const float* __restrict__ x,
                                const void* __restrict__ wq,
                                const float* __restrict__ s,
                                float* __restrict__ out, const int* __restrict__ flag) {
  const bool packed8 = (flag != nullptr) && (*flag != 0);
  size_t idx = (size_t)blockIdx.x * blockDim.x + threadIdx.x;
  int m = (int)(idx / N_DIM), n = (int)(idx % N_DIM);
  const float* xr = x + (size_t)m * K_DIM;
  float acc = 0.f;
  if (!packed8) {
    const int* wr = (const int*)wq + (size_t)n * K_DIM;
    for (int k = 0; k < K_DIM; ++k) acc += xr[k] * (float)wr[k];
  } else {
    const signed char* wr = (const signed char*)wq + (size_t)n * K_DIM;
    for (int k = 0; k < K_DIM; ++k) acc += xr[k] * (float)wr[k];
  }
  out[idx] = acc * s[n];
}

extern "C" void kernel_launch(void* const* d_in, const int* in_sizes, int n_in,
                              void* d_out, int out_size, void* d_ws, size_t ws_size,
                              hipStream_t stream) {
  const float* x = (const float*)d_in[0];
  const void* wq = d_in[1];   // int32 per harness contract; detect_kernel verifies
  const float* sc = (const float*)d_in[2];
  float* out = (float*)d_out;

  const size_t nx = (size_t)M_DIM * K_DIM;  // 33,554,432
  const size_t nw = (size_t)N_DIM * K_DIM;  // 16,777,216
  const size_t need = 16 + (nx + nw) * sizeof(uint16_t);  // ~100.7 MB + flag

  if (ws_size < need) {
    int* flag = (ws_size >= 4) ? (int*)d_ws : nullptr;
    if (flag) detect_kernel<<<1, 256, 0, stream>>>((const int*)wq, flag);
    size_t total = (size_t)M_DIM * N_DIM;
    fallback_kernel<<<(int)(total / 256), 256, 0, stream>>>(x, wq, sc, out, flag);
    return;
  }

  int* flag = (int*)d_ws;                       // first 16 B reserved
  uint16_t* Xb = (uint16_t*)((uint8_t*)d_ws + 16);
  uint16_t* Wb = Xb + nx;

  detect_kernel<<<1, 256, 0, stream>>>((const int*)wq, flag);
  cvt_x_kernel<<<(int)(nx / 8 / 256), 256, 0, stream>>>(x, Xb);
  cvt_w_kernel<<<(int)(nw / 8 / 256), 256, 0, stream>>>(wq, Wb, flag);

  dim3 grid(N_DIM / BN, M_DIM / BM);  // (32, 64)
  gemm_bf16_bt<<<grid, 256, 0, stream>>>(Xb, Wb, sc, out);
}

// Round 3
// 570.043 us; speedup vs baseline: 1.0604x; 1.0604x over previous
//
#include <hip/hip_runtime.h>
#include <stdint.h>
#include <stddef.h>

#define M_DIM 8192
#define N_DIM 4096
#define K_DIM 4096

#define BM 128
#define BN 128
#define BK 64

typedef __bf16 bf16x8 __attribute__((ext_vector_type(8)));
typedef float f32x4 __attribute__((ext_vector_type(4)));

__device__ __forceinline__ void async_load16(void* lds, const void* g) {
  __builtin_amdgcn_global_load_lds(
      (const __attribute__((address_space(1))) void*)g,
      (__attribute__((address_space(3))) void*)lds,
      16, 0, 0);
}

// W int32 -> bf16. Exact: |q|<=127 fits bf16's 8-bit mantissa under any rounding.
__global__ void cvt_w_kernel(const int* __restrict__ w, __bf16* __restrict__ y) {
  size_t i = ((size_t)blockIdx.x * blockDim.x + threadIdx.x) * 8;
  const int4* p = (const int4*)(w + i);
  int4 a = p[0], b = p[1];
  bf16x8 o;
  o[0] = (__bf16)(float)a.x; o[1] = (__bf16)(float)a.y;
  o[2] = (__bf16)(float)a.z; o[3] = (__bf16)(float)a.w;
  o[4] = (__bf16)(float)b.x; o[5] = (__bf16)(float)b.y;
  o[6] = (__bf16)(float)b.z; o[7] = (__bf16)(float)b.w;
  *(bf16x8*)(y + i) = o;
}

// C[M,N] = A[M,K](fp32) * B[N,K](bf16)^T, scaled per column n by scaler[n].
// A staged RAW fp32 via global_load_lds (32 KiB), converted to bf16 at
// fragment read (v_cvt_pk_bf16_f32). B staged bf16 (16 KiB). 128x128 tile,
// BK=64, 4 waves (2x2 of 64x64), XOR chunk swizzle (2-way bank alias = free).
__global__ __launch_bounds__(256, 2) void gemm_fused(
    const float* __restrict__ A, const __bf16* __restrict__ B,
    const float* __restrict__ scaler, float* __restrict__ C) {
  __shared__ __align__(16) uint8_t sA[BM * BK * 4];  // 32 KiB fp32
  __shared__ __align__(16) uint8_t sB[BN * BK * 2];  // 16 KiB bf16

  const int tile_n = blockIdx.x * BN;
  const int tile_m = blockIdx.y * BM;
  const int w    = threadIdx.x >> 6;
  const int lane = threadIdx.x & 63;
  const int q    = lane >> 4;      // quad 0..3
  const int m16  = lane & 15;
  const int wrow = (w >> 1) * 64;  // wave's 64x64 patch
  const int wcol = (w & 1) * 64;

  f32x4 acc[4][4];
#pragma unroll
  for (int i = 0; i < 4; ++i)
#pragma unroll
    for (int j = 0; j < 4; ++j)
      acc[i][j] = (f32x4){0.f, 0.f, 0.f, 0.f};

  for (int kt = 0; kt < K_DIM; kt += BK) {
    // A: 128 rows x 16 chunks(16B = 4 fp32) = 2048 chunks, 8 rounds.
    // Slot g holds (r = g>>4, c = (g&15) ^ (r&15)).
    // lds addr = wave-uniform base + lane*16 (global_load_lds constraint).
#pragma unroll
    for (int p = 0; p < 8; ++p) {
      int g = ((p * 4 + w) << 6) + lane;
      int r = g >> 4;
      int c = (g & 15) ^ (r & 15);
      async_load16(sA + (size_t)g * 16,
                   A + (size_t)(tile_m + r) * K_DIM + kt + c * 4);
    }
    // B: 128 rows x 8 chunks(16B = 8 bf16) = 1024 chunks, 4 rounds.
#pragma unroll
    for (int p = 0; p < 4; ++p) {
      int g = ((p * 4 + w) << 6) + lane;
      int r = g >> 3;
      int c = (g & 7) ^ (r & 7);
      async_load16(sB + (size_t)g * 16,
                   B + (size_t)(tile_n + r) * K_DIM + kt + c * 8);
    }
    __syncthreads();

#pragma unroll
    for (int ks = 0; ks < 2; ++ks) {
      const int ka = (ks << 2) + q;  // 8-elem K group index, 0..7
      bf16x8 af[4], bfr[4];
#pragma unroll
      for (int t = 0; t < 4; ++t) {
        // A fragment: row ra, K elems [ka*8, ka*8+8) = chunks 2ka, 2ka+1.
        int ra = wrow + t * 16 + m16;
        int s0 = (ra << 4) + ((2 * ka) ^ (ra & 15));
        int s1 = (ra << 4) + ((2 * ka + 1) ^ (ra & 15));
        f32x4 a0 = *(const f32x4*)(sA + (size_t)s0 * 16);
        f32x4 a1 = *(const f32x4*)(sA + (size_t)s1 * 16);
        bf16x8 v;
        v[0] = (__bf16)a0[0]; v[1] = (__bf16)a0[1];
        v[2] = (__bf16)a0[2]; v[3] = (__bf16)a0[3];
        v[4] = (__bf16)a1[0]; v[5] = (__bf16)a1[1];
        v[6] = (__bf16)a1[2]; v[7] = (__bf16)a1[3];
        af[t] = v;
        int rb = wcol + t * 16 + m16;
        bfr[t] = *(const bf16x8*)(sB + (size_t)(((rb << 3) + (ka ^ (rb & 7))) << 4));
      }
#pragma unroll
      for (int i = 0; i < 4; ++i)
#pragma unroll
        for (int j = 0; j < 4; ++j)
          acc[i][j] = __builtin_amdgcn_mfma_f32_16x16x32_bf16(
              af[i], bfr[j], acc[i][j], 0, 0, 0);
    }
    __syncthreads();
  }

  // Epilogue: C/D layout col=lane&15, row=(lane>>4)*4+reg. Scale by scaler[col].
#pragma unroll
  for (int j = 0; j < 4; ++j) {
    int col = tile_n + wcol + j * 16 + m16;
    float s = scaler[col];
#pragma unroll
    for (int i = 0; i < 4; ++i) {
      int row0 = tile_m + wrow + i * 16 + q * 4;
#pragma unroll
      for (int r = 0; r < 4; ++r)
        C[(size_t)(row0 + r) * N_DIM + col] = acc[i][j][r] * s;
    }
  }
}

// Correct-but-slow insurance if ws_size can't hold the bf16 weight copy.
__global__ void fallback_kernel(const float* __restrict__ x,
                                const int* __restrict__ wq,
                                const float* __restrict__ s,
                                float* __restrict__ out) {
  size_t idx = (size_t)blockIdx.x * blockDim.x + threadIdx.x;
  int m = (int)(idx / N_DIM), n = (int)(idx % N_DIM);
  const float* xr = x + (size_t)m * K_DIM;
  const int* wr = wq + (size_t)n * K_DIM;
  float acc = 0.f;
  for (int k = 0; k < K_DIM; ++k) acc += xr[k] * (float)wr[k];
  out[idx] = acc * s[n];
}

extern "C" void kernel_launch(void* const* d_in, const int* in_sizes, int n_in,
                              void* d_out, int out_size, void* d_ws, size_t ws_size,
                              hipStream_t stream) {
  const float* x = (const float*)d_in[0];
  const int* wq = (const int*)d_in[1];   // int32 per harness contract (verified R2)
  const float* sc = (const float*)d_in[2];
  float* out = (float*)d_out;

  const size_t nw = (size_t)N_DIM * K_DIM;            // 16,777,216
  const size_t need = nw * sizeof(uint16_t);          // ~33.6 MB

  if (ws_size < need) {
    size_t total = (size_t)M_DIM * N_DIM;
    fallback_kernel<<<(int)(total / 256), 256, 0, stream>>>(x, wq, sc, out);
    return;
  }

  __bf16* Wb = (__bf16*)d_ws;
  cvt_w_kernel<<<(int)(nw / 8 / 256), 256, 0, stream>>>(wq, Wb);

  dim3 grid(N_DIM / BN, M_DIM / BM);  // (32, 64)
  gemm_fused<<<grid, 256, 0, stream>>>(x, Wb, sc, out);
}